// Round 1
// baseline (1535.290 us; speedup 1.0000x reference)
//
#include <hip/hip_runtime.h>
#include <math.h>

// Problem constants
#define B_    256
#define N_    35
#define I_    64
#define H_    256
#define ROWS  8960            // B_*N_
#define ELEMS 2293760L        // ROWS*H_

struct XPtrs { const float* p[12]; };

// ---------------- zero scalar accumulators ----------------
__global__ void zero_kernel(float* accs) {
    if (threadIdx.x < 8) accs[threadIdx.x] = 0.f;
}

// ---------------- adjacency composition (12 views, plain + squared) ----------------
__global__ void compose_kernel(const float* __restrict__ As_, const float* __restrict__ Af_,
                               const float* __restrict__ At_, float* __restrict__ A12,
                               float* __restrict__ A12sq) {
    int blk = blockIdx.x;            // 0..23
    int v = blk / 12, r = blk % 12;
    __shared__ float M[3][N_ * N_];
    for (int i = threadIdx.x; i < N_ * N_; i += blockDim.x) {
        float a = As_[i], f = Af_[i], t = At_[i];
        if (v) { a *= a; f *= f; t *= t; }
        M[0][i] = a; M[1][i] = f; M[2][i] = t;
    }
    __syncthreads();
    const int kind[12] = {0,0,0, 1,1,1,1,1,1, 2,2,2};
    const int ia[12]   = {0,1,2, 0,1,0,2,1,2, 0,0,2};
    const int ib[12]   = {0,1,2, 1,0,2,0,2,1, 1,2,0};
    const int ic[12]   = {0,0,0, 0,0,0,0,0,0, 2,1,1};
    const float* Ma = M[ia[r]];
    const float* Mb = M[ib[r]];
    const float* Mc = M[ic[r]];
    float* dst = (v ? A12sq : A12) + r * N_ * N_;
    for (int i = threadIdx.x; i < N_ * N_; i += blockDim.x) {
        int m = i / N_, n = i % N_;
        float acc;
        if (kind[r] == 0) {
            acc = Ma[i];
        } else if (kind[r] == 1) {
            acc = 0.f;
            for (int p = 0; p < N_; p++) acc += Ma[m*N_+p] * Mb[p*N_+n];
        } else {
            acc = 0.f;
            for (int p = 0; p < N_; p++) {
                float t = 0.f;
                for (int q = 0; q < N_; q++) t += Mb[p*N_+q] * Mc[q*N_+n];
                acc += Ma[m*N_+p] * t;
            }
        }
        dst[i] = acc;
    }
}

// ---------------- basis-composed weights: Wc[r][k][o], k<64 -> comp1*V1, k>=64 -> comp2*V2 ----------------
__global__ void wc_kernel(const float* __restrict__ V1, const float* __restrict__ c1,
                          const float* __restrict__ V2, const float* __restrict__ c2,
                          float* __restrict__ Wc) {
    int idx = blockIdx.x * 256 + threadIdx.x;
    if (idx >= 12 * 128 * 256) return;
    int o = idx & 255;
    int k = (idx >> 8) & 127;
    int r = idx >> 15;
    float acc = 0.f;
    if (k < 64) {
        for (int bb = 0; bb < 4; bb++) acc += c1[r*4+bb] * V1[((long)bb*64 + k)*256 + o];
    } else {
        int kk = k - 64;
        for (int bb = 0; bb < 4; bb++) acc += c2[r*4+bb] * V2[((long)bb*64 + kk)*256 + o];
    }
    Wc[idx] = acc;
}

// ---------------- xA: fold adjacency into x. xAc[r][b*35+m][0:64]=A@x, [64:128]=Asq@x ----------------
__global__ void xa_kernel(XPtrs xp, const float* __restrict__ A12, const float* __restrict__ A12sq,
                          float* __restrict__ xAc) {
    int r = blockIdx.x;      // 0..11
    int b = blockIdx.y;      // 0..255
    __shared__ float sx[N_ * I_];      // 2240
    __shared__ float sA[2][N_ * N_];
    const float* x = xp.p[r] + (long)b * N_ * I_;
    for (int i = threadIdx.x; i < N_ * I_; i += 256) sx[i] = x[i];
    for (int i = threadIdx.x; i < N_ * N_; i += 256) {
        sA[0][i] = A12[r*N_*N_ + i];
        sA[1][i] = A12sq[r*N_*N_ + i];
    }
    __syncthreads();
    int c = threadIdx.x & 127;
    int v = c >> 6;
    int i = c & 63;
    for (int m = threadIdx.x >> 7; m < N_; m += 2) {
        float acc = 0.f;
        const float* Ar = &sA[v][m*N_];
        for (int n = 0; n < N_; n++) acc += Ar[n] * sx[n*I_ + i];
        xAc[((long)r*ROWS + b*N_ + m)*128 + c] = acc;
    }
}

// ---------------- generic fp32 GEMM, 64x64 tile, 4x4 microtile ----------------
// A row-major [M x K], k-split at K0 between A0/A1 (same lda). B row-major [K x N],
// n-split at N0 between B0/B1 (same ldb, rows indexed by global k).
// act: 0 none, 1 relu, 2 sigmoid, 3 GRU-final ((1-z)h + z*tanh(acc)),
//      4 split-relu (relu(partial k<K/2) + relu(partial k>=K/2))
__global__ __launch_bounds__(256)
void gemm_kernel(const float* __restrict__ A0, const float* __restrict__ A1,
                 int K0, int K, int lda,
                 const float* __restrict__ B0, const float* __restrict__ B1,
                 int N0, int ldb,
                 float* __restrict__ C, int ldc,
                 int act,
                 const float* __restrict__ Z, int ldz,
                 const float* __restrict__ Hp, int ldh,
                 long astr, long bstr, long cstr) {
    int bz = blockIdx.z;
    int n0 = blockIdx.x * 64;
    int m0 = blockIdx.y * 64;
    const float* bbase = ((n0 < N0) ? B0 : B1) + bz * bstr;
    int ncol = (n0 < N0) ? n0 : (n0 - N0);
    __shared__ float As[16][68];
    __shared__ float Bs[16][68];
    int tid = threadIdx.x;
    int tx = tid & 15, ty = tid >> 4;
    float acc[4][4] = {{0.f}};
    float accA[4][4] = {{0.f}};   // stashed relu part for act==4
    int ksplit = K >> 1;
    for (int kt = 0; kt < K; kt += 16) {
        const float* aseg; int kk0;
        if (kt < K0) { aseg = A0 + bz * astr; kk0 = kt; }
        else         { aseg = A1 + bz * astr; kk0 = kt - K0; }
#pragma unroll
        for (int j = 0; j < 4; j++) {
            int idx = tid + 256 * j;
            int row = idx >> 4, k = idx & 15;
            As[k][row] = aseg[(long)(m0 + row) * lda + kk0 + k];
        }
#pragma unroll
        for (int j = 0; j < 4; j++) {
            int idx = tid + 256 * j;
            int col = idx & 63, kr = idx >> 6;
            Bs[kr][col] = bbase[(long)(kt + kr) * ldb + ncol + col];
        }
        __syncthreads();
#pragma unroll
        for (int k = 0; k < 16; k++) {
            float ar[4], br[4];
#pragma unroll
            for (int i = 0; i < 4; i++) ar[i] = As[k][ty*4 + i];
#pragma unroll
            for (int j = 0; j < 4; j++) br[j] = Bs[k][tx*4 + j];
#pragma unroll
            for (int i = 0; i < 4; i++) {
#pragma unroll
                for (int j = 0; j < 4; j++) acc[i][j] += ar[i] * br[j];
            }
        }
        __syncthreads();
        if (act == 4 && (kt + 16) == ksplit) {
#pragma unroll
            for (int i = 0; i < 4; i++) {
#pragma unroll
                for (int j = 0; j < 4; j++) {
                    accA[i][j] = fmaxf(acc[i][j], 0.f);
                    acc[i][j] = 0.f;
                }
            }
        }
    }
    float* c = C + bz * cstr;
#pragma unroll
    for (int i = 0; i < 4; i++) {
        long row = m0 + ty*4 + i;
#pragma unroll
        for (int j = 0; j < 4; j++) {
            int col = n0 + tx*4 + j;
            float v = acc[i][j];
            if (act == 1)       v = fmaxf(v, 0.f);
            else if (act == 2)  v = 1.f / (1.f + expf(-v));
            else if (act == 3) {
                float zz = Z[row * ldz + col];
                float hv = Hp[row * ldh + col];
                v = (1.f - zz) * hv + zz * tanhf(v);
            } else if (act == 4) {
                v = accA[i][j] + fmaxf(v, 0.f);
            }
            c[row * ldc + col] = v;
        }
    }
}

// ---------------- msh (shared-matrix linear over node axis) + sim + com, pair version ----------------
__global__ void msh_pair_kernel(const float* __restrict__ oa, const float* __restrict__ ob,
                                const float* __restrict__ S, float* __restrict__ com,
                                float* __restrict__ acc) {
    int b = blockIdx.x;
    int h0 = blockIdx.y * 64;
    __shared__ float sa[N_][64];
    __shared__ float sb[N_][64];
    __shared__ float sS[N_ * N_];
    __shared__ float wred[4];
    const float* pa = oa + (long)b * N_ * H_;
    const float* pb = ob + (long)b * N_ * H_;
    for (int i = threadIdx.x; i < N_ * 64; i += 256) {
        int n = i >> 6, hh = i & 63;
        sa[n][hh] = pa[n*H_ + h0 + hh];
        sb[n][hh] = pb[n*H_ + h0 + hh];
    }
    for (int i = threadIdx.x; i < N_ * N_; i += 256) sS[i] = S[i];
    __syncthreads();
    int hh = threadIdx.x & 63;
    int mq = threadIdx.x >> 6;
    float lsum = 0.f;
    for (int mm = mq; mm < N_; mm += 4) {
        float ma = 0.f, mb = 0.f;
        for (int n = 0; n < N_; n++) {
            float s = sS[n*N_ + mm];
            ma += sa[n][hh] * s;
            mb += sb[n][hh] * s;
        }
        com[((long)b*N_ + mm)*H_ + h0 + hh] = 0.5f * (ma + mb);
        float d = ma - mb;
        lsum += d * d;
    }
    for (int off = 32; off > 0; off >>= 1) lsum += __shfl_down(lsum, off);
    if ((threadIdx.x & 63) == 0) wred[threadIdx.x >> 6] = lsum;
    __syncthreads();
    if (threadIdx.x == 0) atomicAdd(acc, wred[0] + wred[1] + wred[2] + wred[3]);
}

// ---------------- triple version (sft) ----------------
__global__ void msh_tri_kernel(const float* __restrict__ oa, const float* __restrict__ ob,
                               const float* __restrict__ oc, const float* __restrict__ S,
                               float* __restrict__ com, float* __restrict__ acc) {
    int b = blockIdx.x;
    int h0 = blockIdx.y * 64;
    __shared__ float sa[N_][64];
    __shared__ float sb[N_][64];
    __shared__ float sc[N_][64];
    __shared__ float sS[N_ * N_];
    __shared__ float wred[4];
    const float* pa = oa + (long)b * N_ * H_;
    const float* pb = ob + (long)b * N_ * H_;
    const float* pc = oc + (long)b * N_ * H_;
    for (int i = threadIdx.x; i < N_ * 64; i += 256) {
        int n = i >> 6, hh = i & 63;
        sa[n][hh] = pa[n*H_ + h0 + hh];
        sb[n][hh] = pb[n*H_ + h0 + hh];
        sc[n][hh] = pc[n*H_ + h0 + hh];
    }
    for (int i = threadIdx.x; i < N_ * N_; i += 256) sS[i] = S[i];
    __syncthreads();
    int hh = threadIdx.x & 63;
    int mq = threadIdx.x >> 6;
    float lsum = 0.f;
    const float third = 1.f / 3.f;
    for (int mm = mq; mm < N_; mm += 4) {
        float ma = 0.f, mb = 0.f, mc = 0.f;
        for (int n = 0; n < N_; n++) {
            float s = sS[n*N_ + mm];
            ma += sa[n][hh] * s;
            mb += sb[n][hh] * s;
            mc += sc[n][hh] * s;
        }
        com[((long)b*N_ + mm)*H_ + h0 + hh] = (ma + mb + mc) * third;
        float d1 = ma - mb, d2 = ma - mc, d3 = mb - mc;
        lsum += d1*d1 + d2*d2 + d3*d3;
    }
    for (int off = 32; off > 0; off >>= 1) lsum += __shfl_down(lsum, off);
    if ((threadIdx.x & 63) == 0) wred[threadIdx.x >> 6] = lsum;
    __syncthreads();
    if (threadIdx.x == 0) atomicAdd(acc, wred[0] + wred[1] + wred[2] + wred[3]);
}

// ---------------- L1 norms of the 4 S matrices (output order: st, sf, ft, sft) ----------------
__global__ void l1_kernel(const float* __restrict__ S0, const float* __restrict__ S1,
                          const float* __restrict__ S2, const float* __restrict__ S3,
                          float* __restrict__ outp) {
    const float* mats[4] = {S0, S1, S2, S3};
    const float* S = mats[blockIdx.x];
    float s = 0.f;
    for (int i = threadIdx.x; i < N_ * N_; i += 256) s += fabsf(S[i]);
    for (int off = 32; off > 0; off >>= 1) s += __shfl_down(s, off);
    __shared__ float wred[4];
    if ((threadIdx.x & 63) == 0) wred[threadIdx.x >> 6] = s;
    __syncthreads();
    if (threadIdx.x == 0) outp[blockIdx.x] = wred[0] + wred[1] + wred[2] + wred[3];
}

// ---------------- finalize sims ----------------
__global__ void fin_kernel(const float* __restrict__ accs, float* __restrict__ outp) {
    if (threadIdx.x == 0) {
        float inv = 1.f / 2293760.f;
        outp[0] = accs[0] * inv;
        outp[1] = accs[1] * inv;
        outp[2] = accs[2] * inv;
        outp[3] = accs[3] * inv;   // triple kernel accumulated all three pair-sums here
    }
}

// ---------------- r*h elementwise ----------------
__global__ void rh_kernel(const float* __restrict__ gates, const float* __restrict__ h,
                          float* __restrict__ rh) {
    long idx = (long)blockIdx.x * 256 + threadIdx.x;   // grid sized exactly to ELEMS
    long row = idx >> 8;
    int col = (int)(idx & 255);
    rh[idx] = gates[row * 512 + col] * h[idx];
}

extern "C" void kernel_launch(void* const* d_in, const int* in_sizes, int n_in,
                              void* d_out, int out_size, void* d_ws, size_t ws_size,
                              hipStream_t stream) {
    const float* const* in = (const float* const*)d_in;
    float* out = (float*)d_out;
    float* ws  = (float*)d_ws;

    // workspace layout (floats); total ~44.0M floats = 176 MB
    float* A12   = ws;                              // 12*35*35
    float* A12sq = A12 + 12*N_*N_;
    float* Wc    = A12sq + 12*N_*N_;                // 12*128*256
    float* accs  = Wc + 12*128*256;                 // 8 (+pad 64)
    float* xAc   = accs + 64;                       // 12*8960*128 = 13762560
    float* gout  = xAc + (long)12*ROWS*128;         // 12*ELEMS = 27525120
    float* com   = xAc;                             // alias: xAc dead after gcn GEMM (4*ELEMS)
    float* gates = xAc + 4L*ELEMS;                  // 8960*512 (fits exactly in rest of xAc)
    float* rh    = gout + 12L*ELEMS;                // ELEMS

    XPtrs xp;
    for (int i = 0; i < 12; i++) xp.p[i] = in[i];

    zero_kernel<<<1, 64, 0, stream>>>(accs);
    compose_kernel<<<24, 256, 0, stream>>>(in[12], in[13], in[14], A12, A12sq);
    wc_kernel<<<(12*128*256 + 255)/256, 256, 0, stream>>>(in[22], in[23], in[24], in[25], Wc);
    xa_kernel<<<dim3(12, 256), 256, 0, stream>>>(xp, A12, A12sq, xAc);

    // GCN output: gout[r] = relu(xA1@W1) + relu(xA2@W2), batched over 12 rels (act=4 split-relu at K/2)
    gemm_kernel<<<dim3(4, 140, 12), 256, 0, stream>>>(
        xAc, (const float*)nullptr, 128, 128, 128,
        Wc, (const float*)nullptr, 256, 256,
        gout, 256, 4,
        (const float*)nullptr, 0, (const float*)nullptr, 0,
        (long)ROWS*128, (long)128*256, (long)ROWS*256);

    // msh + sim + com
    msh_pair_kernel<<<dim3(256, 4), 256, 0, stream>>>(gout + 3L*ELEMS, gout + 4L*ELEMS, in[26], com + 0L*ELEMS, accs + 0);
    msh_pair_kernel<<<dim3(256, 4), 256, 0, stream>>>(gout + 5L*ELEMS, gout + 6L*ELEMS, in[27], com + 1L*ELEMS, accs + 1);
    msh_pair_kernel<<<dim3(256, 4), 256, 0, stream>>>(gout + 7L*ELEMS, gout + 8L*ELEMS, in[28], com + 2L*ELEMS, accs + 2);
    msh_tri_kernel <<<dim3(256, 4), 256, 0, stream>>>(gout + 9L*ELEMS, gout + 10L*ELEMS, gout + 11L*ELEMS,
                                                      in[29], com + 3L*ELEMS, accs + 3);

    // scalar outputs: sims at out+7*ELEMS+0..3, l1 at +4..7 (order: st, sf, ft, sft)
    l1_kernel<<<4, 256, 0, stream>>>(in[27], in[26], in[28], in[29], out + 7L*ELEMS + 4);
    fin_kernel<<<1, 64, 0, stream>>>(accs, out + 7L*ELEMS);

    // 7 GRUs
    for (int g = 0; g < 7; g++) {
        const float* o_g  = (g < 3) ? gout + (long)g*ELEMS : com + (long)(g - 3)*ELEMS;
        const float* h_g  = in[15 + g];
        const float* Wr_g = in[30] + (long)g*512*256;
        const float* Wz_g = in[31] + (long)g*512*256;
        const float* Wh_g = in[32] + (long)g*512*256;

        // gates: C[:,0:256]=sigmoid([o|h]@Wr), C[:,256:512]=sigmoid([o|h]@Wz)
        gemm_kernel<<<dim3(8, 140, 1), 256, 0, stream>>>(
            o_g, h_g, 256, 512, 256,
            Wr_g, Wz_g, 256, 256,
            gates, 512, 2,
            (const float*)nullptr, 0, (const float*)nullptr, 0,
            0L, 0L, 0L);

        // rh = r * h
        rh_kernel<<<ROWS, 256, 0, stream>>>(gates, h_g, rh);

        // h_out = (1-z)*h + z*tanh([rh|o]@Wh), written directly to d_out
        gemm_kernel<<<dim3(4, 140, 1), 256, 0, stream>>>(
            rh, o_g, 256, 512, 256,
            Wh_g, (const float*)nullptr, 256, 256,
            out + (long)g*ELEMS, 256, 3,
            gates + 256, 512, h_g, 256,
            0L, 0L, 0L);
    }
}

// Round 2
// 729.463 us; speedup vs baseline: 2.1047x; 2.1047x over previous
//
#include <hip/hip_runtime.h>
#include <math.h>

// Problem constants
#define B_    256
#define N_    35
#define I_    64
#define H_    256
#define ROWS  8960            // B_*N_
#define ELEMS 2293760L        // ROWS*H_

typedef __bf16 bf16x8 __attribute__((ext_vector_type(8)));
typedef float f32x4 __attribute__((ext_vector_type(4)));

struct XPtrs { const float* p[12]; };
struct HPtrs { const float* p[7]; };

#define GLOAD_LDS16(g, l) __builtin_amdgcn_global_load_lds( \
    (const __attribute__((address_space(1))) unsigned int*)(g), \
    (__attribute__((address_space(3))) unsigned int*)(l), 16, 0, 0)

// ---------------- zero scalar accumulators ----------------
__global__ void zero_kernel(float* accs) {
    if (threadIdx.x < 8) accs[threadIdx.x] = 0.f;
}

// ---------------- adjacency composition (12 views, plain + squared) ----------------
__global__ void compose_kernel(const float* __restrict__ As_, const float* __restrict__ Af_,
                               const float* __restrict__ At_, float* __restrict__ A12,
                               float* __restrict__ A12sq) {
    int blk = blockIdx.x;            // 0..23
    int v = blk / 12, r = blk % 12;
    __shared__ float M[3][N_ * N_];
    for (int i = threadIdx.x; i < N_ * N_; i += blockDim.x) {
        float a = As_[i], f = Af_[i], t = At_[i];
        if (v) { a *= a; f *= f; t *= t; }
        M[0][i] = a; M[1][i] = f; M[2][i] = t;
    }
    __syncthreads();
    const int kind[12] = {0,0,0, 1,1,1,1,1,1, 2,2,2};
    const int ia[12]   = {0,1,2, 0,1,0,2,1,2, 0,0,2};
    const int ib[12]   = {0,1,2, 1,0,2,0,2,1, 1,2,0};
    const int ic[12]   = {0,0,0, 0,0,0,0,0,0, 2,1,1};
    const float* Ma = M[ia[r]];
    const float* Mb = M[ib[r]];
    const float* Mc = M[ic[r]];
    float* dst = (v ? A12sq : A12) + r * N_ * N_;
    for (int i = threadIdx.x; i < N_ * N_; i += blockDim.x) {
        int m = i / N_, n = i % N_;
        float acc;
        if (kind[r] == 0) {
            acc = Ma[i];
        } else if (kind[r] == 1) {
            acc = 0.f;
            for (int p = 0; p < N_; p++) acc += Ma[m*N_+p] * Mb[p*N_+n];
        } else {
            acc = 0.f;
            for (int p = 0; p < N_; p++) {
                float t = 0.f;
                for (int q = 0; q < N_; q++) t += Mb[p*N_+q] * Mc[q*N_+n];
                acc += Ma[m*N_+p] * t;
            }
        }
        dst[i] = acc;
    }
}

// ---------------- basis-composed weights, transposed to [r][o][k] bf16 ----------------
__global__ void wc_kernel(const float* __restrict__ V1, const float* __restrict__ c1,
                          const float* __restrict__ V2, const float* __restrict__ c2,
                          __bf16* __restrict__ WcT) {
    int idx = blockIdx.x * 256 + threadIdx.x;   // 12*256*128
    int k = idx & 127;
    int o = (idx >> 7) & 255;
    int r = idx >> 15;
    float acc = 0.f;
    if (k < 64) {
        for (int bb = 0; bb < 4; bb++) acc += c1[r*4+bb] * V1[((long)bb*64 + k)*256 + o];
    } else {
        int kk = k - 64;
        for (int bb = 0; bb < 4; bb++) acc += c2[r*4+bb] * V2[((long)bb*64 + kk)*256 + o];
    }
    WcT[idx] = (__bf16)acc;
}

// ---------------- GRU weight transpose: [7][512k][256n] fp32 -> [mat][g][256n][512k] bf16 ----------------
__global__ void wt_kernel(const float* __restrict__ Wr, const float* __restrict__ Wz,
                          const float* __restrict__ Wh, __bf16* __restrict__ WT) {
    int z = blockIdx.z;              // 0..20
    int mat = z / 7, g = z % 7;
    const float* srcs[3] = {Wr, Wz, Wh};
    const float* src = srcs[mat] + (long)g * 512 * 256;
    __bf16* dst = WT + ((long)mat * 7 + g) * 256 * 512;
    int n0 = blockIdx.x * 64;        // grid.x = 4
    int k0 = blockIdx.y * 64;        // grid.y = 8
    __shared__ float T[64][65];
    int c = threadIdx.x & 63, r0 = threadIdx.x >> 6;
    for (int r = r0; r < 64; r += 4)
        T[r][c] = src[(long)(k0 + r) * 256 + n0 + c];
    __syncthreads();
    for (int n = r0; n < 64; n += 4)
        dst[(long)(n0 + n) * 512 + k0 + c] = (__bf16)T[c][n];
}

// ---------------- hidden fp32 -> bf16 cast ----------------
__global__ void hcast_kernel(HPtrs hp, __bf16* __restrict__ out) {
    int g = blockIdx.y;
    long idx = ((long)blockIdx.x * 256 + threadIdx.x) * 4;   // grid.x = ELEMS/4/256 = 2240
    float4 v = *(const float4*)(hp.p[g] + idx);
    __bf16* o = out + (long)g * ELEMS + idx;
    o[0] = (__bf16)v.x; o[1] = (__bf16)v.y; o[2] = (__bf16)v.z; o[3] = (__bf16)v.w;
}

// ---------------- xA fold: xAc[r][row][0:64]=A@x, [64:128]=Asq@x, bf16 ----------------
__global__ void xa_kernel(XPtrs xp, const float* __restrict__ A12, const float* __restrict__ A12sq,
                          __bf16* __restrict__ xAc) {
    int r = blockIdx.x;      // 0..11
    int b = blockIdx.y;      // 0..255
    __shared__ float sx[N_ * I_];
    __shared__ float sA[2][N_ * N_];
    const float* x = xp.p[r] + (long)b * N_ * I_;
    for (int i = threadIdx.x; i < N_ * I_; i += 256) sx[i] = x[i];
    for (int i = threadIdx.x; i < N_ * N_; i += 256) {
        sA[0][i] = A12[r*N_*N_ + i];
        sA[1][i] = A12sq[r*N_*N_ + i];
    }
    __syncthreads();
    int c = threadIdx.x & 127;
    int v = c >> 6;
    int i = c & 63;
    for (int m = threadIdx.x >> 7; m < N_; m += 2) {
        float acc = 0.f;
        const float* Ar = &sA[v][m*N_];
        for (int n = 0; n < N_; n++) acc += Ar[n] * sx[n*I_ + i];
        xAc[((long)r*ROWS + b*N_ + m)*128 + c] = (__bf16)acc;
    }
}

// ---------------- bf16 MFMA GEMM, 64x64 tile, 4 waves x 32x32 ----------------
// A row-major [M][K] bf16, k-split at K0 between A0/A1 (same lda).
// B is B^T: row-major [N][K] bf16, n-split at N0 between B0/B1 (same ldb).
// act: 2 sigmoid (fp32 out), 3 GRU-final (fp32 out), 4 split-relu sum (bf16 out)
__global__ __launch_bounds__(256)
void gemm_bf16(const __bf16* __restrict__ A0, const __bf16* __restrict__ A1,
               int K0, int K, int lda,
               const __bf16* __restrict__ B0, const __bf16* __restrict__ B1,
               int N0, int ldb,
               void* __restrict__ Cp, int ldc,
               int act,
               const float* __restrict__ Z, int ldz,
               const float* __restrict__ Hp, int ldh,
               long astr, long bstr, long cstr) {
    int bz = blockIdx.z;
    int n0 = blockIdx.x * 64;
    int m0 = blockIdx.y * 64;
    const __bf16* bbase = ((n0 < N0) ? B0 : B1) + bz * bstr;
    int nloc = (n0 < N0) ? n0 : (n0 - N0);
    __shared__ __bf16 As[64 * 32];
    __shared__ __bf16 Bs[64 * 32];
    int tid = threadIdx.x;
    int lane = tid & 63;
    int w = tid >> 6;
    int wm = (w & 1) * 32, wn = (w >> 1) * 32;
    int l15 = lane & 15, q = lane >> 4;
    f32x4 acc[2][2] = {};
    f32x4 accA[2][2] = {};
    int ksplit = K >> 1;

    // staging: wave w stages rows [w*16, w*16+16) of each tile; lane -> (row, 16B seg)
    int srow = w * 16 + (lane >> 2);
    int skoff = (lane & 3) * 8;
    __bf16* lds_a = As + w * 512;          // wave-uniform base, +lane*16B implicit
    __bf16* lds_b = Bs + w * 512;
    const __bf16* brow = bbase + (long)(nloc + srow) * ldb + skoff;

    for (int kt = 0; kt < K; kt += 32) {
        const __bf16* aseg; int kk;
        if (kt < K0) { aseg = A0 + bz * astr; kk = kt; }
        else         { aseg = A1 + bz * astr; kk = kt - K0; }
        GLOAD_LDS16(aseg + (long)(m0 + srow) * lda + kk + skoff, lds_a);
        GLOAD_LDS16(brow + kt, lds_b);
        __syncthreads();
        bf16x8 af0 = *(const bf16x8*)(As + (wm + l15) * 32 + q * 8);
        bf16x8 af1 = *(const bf16x8*)(As + (wm + 16 + l15) * 32 + q * 8);
        bf16x8 bf0 = *(const bf16x8*)(Bs + (wn + l15) * 32 + q * 8);
        bf16x8 bf1 = *(const bf16x8*)(Bs + (wn + 16 + l15) * 32 + q * 8);
        acc[0][0] = __builtin_amdgcn_mfma_f32_16x16x32_bf16(af0, bf0, acc[0][0], 0, 0, 0);
        acc[0][1] = __builtin_amdgcn_mfma_f32_16x16x32_bf16(af0, bf1, acc[0][1], 0, 0, 0);
        acc[1][0] = __builtin_amdgcn_mfma_f32_16x16x32_bf16(af1, bf0, acc[1][0], 0, 0, 0);
        acc[1][1] = __builtin_amdgcn_mfma_f32_16x16x32_bf16(af1, bf1, acc[1][1], 0, 0, 0);
        __syncthreads();
        if (act == 4 && (kt + 32) == ksplit) {
#pragma unroll
            for (int mt = 0; mt < 2; mt++)
#pragma unroll
                for (int nt = 0; nt < 2; nt++)
#pragma unroll
                    for (int r = 0; r < 4; r++) {
                        accA[mt][nt][r] = fmaxf(acc[mt][nt][r], 0.f);
                        acc[mt][nt][r] = 0.f;
                    }
        }
    }

#pragma unroll
    for (int mt = 0; mt < 2; mt++) {
#pragma unroll
        for (int nt = 0; nt < 2; nt++) {
#pragma unroll
            for (int r = 0; r < 4; r++) {
                long row = m0 + wm + mt*16 + q*4 + r;
                int col  = n0 + wn + nt*16 + l15;
                float v = acc[mt][nt][r];
                if (act == 2) {
                    ((float*)Cp)[bz*cstr + row * ldc + col] = 1.f / (1.f + expf(-v));
                } else if (act == 3) {
                    float zz = Z[row * ldz + col];
                    float hv = Hp[row * ldh + col];
                    ((float*)Cp)[bz*cstr + row * ldc + col] = (1.f - zz) * hv + zz * tanhf(v);
                } else {  // act 4
                    ((__bf16*)Cp)[bz*cstr + row * ldc + col] = (__bf16)(accA[mt][nt][r] + fmaxf(v, 0.f));
                }
            }
        }
    }
}

// ---------------- msh + sim + com, pair version (bf16 in, bf16 com out) ----------------
__global__ void msh_pair_kernel(const __bf16* __restrict__ oa, const __bf16* __restrict__ ob,
                                const float* __restrict__ S, __bf16* __restrict__ com,
                                float* __restrict__ acc) {
    int b = blockIdx.x;
    int h0 = blockIdx.y * 64;
    __shared__ float sa[N_][64];
    __shared__ float sb[N_][64];
    __shared__ float sS[N_ * N_];
    __shared__ float wred[4];
    const __bf16* pa = oa + (long)b * N_ * H_;
    const __bf16* pb = ob + (long)b * N_ * H_;
    for (int i = threadIdx.x; i < N_ * 64; i += 256) {
        int n = i >> 6, hh = i & 63;
        sa[n][hh] = (float)pa[n*H_ + h0 + hh];
        sb[n][hh] = (float)pb[n*H_ + h0 + hh];
    }
    for (int i = threadIdx.x; i < N_ * N_; i += 256) sS[i] = S[i];
    __syncthreads();
    int hh = threadIdx.x & 63;
    int mq = threadIdx.x >> 6;
    float lsum = 0.f;
    for (int mm = mq; mm < N_; mm += 4) {
        float ma = 0.f, mb = 0.f;
        for (int n = 0; n < N_; n++) {
            float s = sS[n*N_ + mm];
            ma += sa[n][hh] * s;
            mb += sb[n][hh] * s;
        }
        com[((long)b*N_ + mm)*H_ + h0 + hh] = (__bf16)(0.5f * (ma + mb));
        float d = ma - mb;
        lsum += d * d;
    }
    for (int off = 32; off > 0; off >>= 1) lsum += __shfl_down(lsum, off);
    if ((threadIdx.x & 63) == 0) wred[threadIdx.x >> 6] = lsum;
    __syncthreads();
    if (threadIdx.x == 0) atomicAdd(acc, wred[0] + wred[1] + wred[2] + wred[3]);
}

// ---------------- triple version (sft) ----------------
__global__ void msh_tri_kernel(const __bf16* __restrict__ oa, const __bf16* __restrict__ ob,
                               const __bf16* __restrict__ oc, const float* __restrict__ S,
                               __bf16* __restrict__ com, float* __restrict__ acc) {
    int b = blockIdx.x;
    int h0 = blockIdx.y * 64;
    __shared__ float sa[N_][64];
    __shared__ float sb[N_][64];
    __shared__ float sc[N_][64];
    __shared__ float sS[N_ * N_];
    __shared__ float wred[4];
    const __bf16* pa = oa + (long)b * N_ * H_;
    const __bf16* pb = ob + (long)b * N_ * H_;
    const __bf16* pc = oc + (long)b * N_ * H_;
    for (int i = threadIdx.x; i < N_ * 64; i += 256) {
        int n = i >> 6, hh = i & 63;
        sa[n][hh] = (float)pa[n*H_ + h0 + hh];
        sb[n][hh] = (float)pb[n*H_ + h0 + hh];
        sc[n][hh] = (float)pc[n*H_ + h0 + hh];
    }
    for (int i = threadIdx.x; i < N_ * N_; i += 256) sS[i] = S[i];
    __syncthreads();
    int hh = threadIdx.x & 63;
    int mq = threadIdx.x >> 6;
    float lsum = 0.f;
    const float third = 1.f / 3.f;
    for (int mm = mq; mm < N_; mm += 4) {
        float ma = 0.f, mb = 0.f, mc = 0.f;
        for (int n = 0; n < N_; n++) {
            float s = sS[n*N_ + mm];
            ma += sa[n][hh] * s;
            mb += sb[n][hh] * s;
            mc += sc[n][hh] * s;
        }
        com[((long)b*N_ + mm)*H_ + h0 + hh] = (__bf16)((ma + mb + mc) * third);
        float d1 = ma - mb, d2 = ma - mc, d3 = mb - mc;
        lsum += d1*d1 + d2*d2 + d3*d3;
    }
    for (int off = 32; off > 0; off >>= 1) lsum += __shfl_down(lsum, off);
    if ((threadIdx.x & 63) == 0) wred[threadIdx.x >> 6] = lsum;
    __syncthreads();
    if (threadIdx.x == 0) atomicAdd(acc, wred[0] + wred[1] + wred[2] + wred[3]);
}

// ---------------- L1 norms (output order: st, sf, ft, sft) ----------------
__global__ void l1_kernel(const float* __restrict__ S0, const float* __restrict__ S1,
                          const float* __restrict__ S2, const float* __restrict__ S3,
                          float* __restrict__ outp) {
    const float* mats[4] = {S0, S1, S2, S3};
    const float* S = mats[blockIdx.x];
    float s = 0.f;
    for (int i = threadIdx.x; i < N_ * N_; i += 256) s += fabsf(S[i]);
    for (int off = 32; off > 0; off >>= 1) s += __shfl_down(s, off);
    __shared__ float wred[4];
    if ((threadIdx.x & 63) == 0) wred[threadIdx.x >> 6] = s;
    __syncthreads();
    if (threadIdx.x == 0) outp[blockIdx.x] = wred[0] + wred[1] + wred[2] + wred[3];
}

// ---------------- finalize sims ----------------
__global__ void fin_kernel(const float* __restrict__ accs, float* __restrict__ outp) {
    if (threadIdx.x == 0) {
        float inv = 1.f / 2293760.f;
        outp[0] = accs[0] * inv;
        outp[1] = accs[1] * inv;
        outp[2] = accs[2] * inv;
        outp[3] = accs[3] * inv;
    }
}

// ---------------- r*h elementwise -> bf16 ----------------
__global__ void rh_kernel(const float* __restrict__ gates, const float* __restrict__ h,
                          __bf16* __restrict__ rh) {
    long idx = (long)blockIdx.x * 256 + threadIdx.x;   // ELEMS threads
    long row = idx >> 8;
    int col = (int)(idx & 255);
    rh[idx] = (__bf16)(gates[row * 512 + col] * h[idx]);
}

extern "C" void kernel_launch(void* const* d_in, const int* in_sizes, int n_in,
                              void* d_out, int out_size, void* d_ws, size_t ws_size,
                              hipStream_t stream) {
    const float* const* in = (const float* const*)d_in;
    float* out = (float*)d_out;
    char* ws = (char*)d_ws;

    // byte-offset workspace layout (~162 MB)
    size_t off = 0;
    auto alloc = [&](size_t bytes) { size_t o = off; off += (bytes + 255) & ~(size_t)255; return o; };
    float*  A12   = (float*)(ws + alloc(12*N_*N_*4));
    float*  A12sq = (float*)(ws + alloc(12*N_*N_*4));
    __bf16* WcT   = (__bf16*)(ws + alloc((size_t)12*256*128*2));
    __bf16* WT    = (__bf16*)(ws + alloc((size_t)21*256*512*2));
    float*  accs  = (float*)(ws + alloc(256));
    __bf16* xAc   = (__bf16*)(ws + alloc((size_t)12*ROWS*128*2));
    __bf16* gout  = (__bf16*)(ws + alloc((size_t)12*ELEMS*2));
    __bf16* com   = (__bf16*)(ws + alloc((size_t)4*ELEMS*2));
    __bf16* hbf   = (__bf16*)(ws + alloc((size_t)7*ELEMS*2));
    float*  gates = (float*)(ws + alloc((size_t)ROWS*512*4));
    __bf16* rh    = (__bf16*)(ws + alloc((size_t)ELEMS*2));

    XPtrs xp;
    for (int i = 0; i < 12; i++) xp.p[i] = in[i];
    HPtrs hp;
    for (int i = 0; i < 7; i++) hp.p[i] = in[15 + i];

    zero_kernel<<<1, 64, 0, stream>>>(accs);
    compose_kernel<<<24, 256, 0, stream>>>(in[12], in[13], in[14], A12, A12sq);
    wc_kernel<<<(12*128*256)/256, 256, 0, stream>>>(in[22], in[23], in[24], in[25], WcT);
    wt_kernel<<<dim3(4, 8, 21), 256, 0, stream>>>(in[30], in[31], in[32], WT);
    hcast_kernel<<<dim3(2240, 7), 256, 0, stream>>>(hp, hbf);
    xa_kernel<<<dim3(12, 256), 256, 0, stream>>>(xp, A12, A12sq, xAc);

    // GCN: gout[r] = relu(xA1@W1) + relu(xA2@W2)  (act=4 split-relu at K/2=64)
    gemm_bf16<<<dim3(4, 140, 12), 256, 0, stream>>>(
        xAc, (const __bf16*)nullptr, 128, 128, 128,
        WcT, (const __bf16*)nullptr, 256, 128,
        gout, 256, 4,
        (const float*)nullptr, 0, (const float*)nullptr, 0,
        (long)ROWS*128, (long)256*128, ELEMS);

    // msh + sim + com
    msh_pair_kernel<<<dim3(256, 4), 256, 0, stream>>>(gout + 3L*ELEMS, gout + 4L*ELEMS, in[26], com + 0L*ELEMS, accs + 0);
    msh_pair_kernel<<<dim3(256, 4), 256, 0, stream>>>(gout + 5L*ELEMS, gout + 6L*ELEMS, in[27], com + 1L*ELEMS, accs + 1);
    msh_pair_kernel<<<dim3(256, 4), 256, 0, stream>>>(gout + 7L*ELEMS, gout + 8L*ELEMS, in[28], com + 2L*ELEMS, accs + 2);
    msh_tri_kernel <<<dim3(256, 4), 256, 0, stream>>>(gout + 9L*ELEMS, gout + 10L*ELEMS, gout + 11L*ELEMS,
                                                      in[29], com + 3L*ELEMS, accs + 3);

    l1_kernel<<<4, 256, 0, stream>>>(in[27], in[26], in[28], in[29], out + 7L*ELEMS + 4);
    fin_kernel<<<1, 64, 0, stream>>>(accs, out + 7L*ELEMS);

    // 7 GRUs
    for (int g = 0; g < 7; g++) {
        const __bf16* o_g  = (g < 3) ? gout + (long)g*ELEMS : com + (long)(g - 3)*ELEMS;
        const __bf16* h_g  = hbf + (long)g*ELEMS;
        const __bf16* WrT_g = WT + (long)g*131072;
        const __bf16* WzT_g = WT + (long)(7 + g)*131072;
        const __bf16* WhT_g = WT + (long)(14 + g)*131072;

        // gates: C[:,0:256]=sigmoid([o|h]@Wr), C[:,256:512]=sigmoid([o|h]@Wz)
        gemm_bf16<<<dim3(8, 140, 1), 256, 0, stream>>>(
            o_g, h_g, 256, 512, 256,
            WrT_g, WzT_g, 256, 512,
            gates, 512, 2,
            (const float*)nullptr, 0, (const float*)nullptr, 0,
            0L, 0L, 0L);

        // rh = r * h (fp32 math, bf16 out)
        rh_kernel<<<ROWS, 256, 0, stream>>>(gates, in[15 + g], rh);

        // h_out = (1-z)*h + z*tanh([rh|o]@Wh), fp32 to d_out
        gemm_bf16<<<dim3(4, 140, 1), 256, 0, stream>>>(
            rh, o_g, 256, 512, 256,
            WhT_g, (const __bf16*)nullptr, 256, 512,
            out + (long)g*ELEMS, 256, 3,
            gates + 256, 512, in[15 + g], 256,
            0L, 0L, 0L);
    }
}

// Round 3
// 688.110 us; speedup vs baseline: 2.2312x; 1.0601x over previous
//
#include <hip/hip_runtime.h>
#include <math.h>

// Problem constants
#define B_    256
#define N_    35
#define I_    64
#define H_    256
#define ROWS  8960            // B_*N_
#define ELEMS 2293760L        // ROWS*H_

typedef __bf16 bf16x8 __attribute__((ext_vector_type(8)));
typedef float f32x4 __attribute__((ext_vector_type(4)));

struct XPtrs { const float* p[12]; };
struct HPtrs { const float* p[7]; };
struct GB    { const __bf16* a0[12]; const __bf16* a1[12]; const float* hp[12]; };
struct MshA  { const __bf16* oa[4]; const __bf16* ob[4]; const __bf16* oc[4];
               const float* S[4]; __bf16* com; float* accs; };

#define GLOAD_LDS16(g, l) __builtin_amdgcn_global_load_lds( \
    (const __attribute__((address_space(1))) unsigned int*)(g), \
    (__attribute__((address_space(3))) unsigned int*)(l), 16, 0, 0)

// ---------------- prep: zero accs (blk 28) + compose adjacencies (blk 0..23) + L1 (blk 24..27) ----
__global__ void prep_kernel(const float* __restrict__ As_, const float* __restrict__ Af_,
                            const float* __restrict__ At_, float* __restrict__ A12,
                            float* __restrict__ A12sq,
                            const float* __restrict__ S0, const float* __restrict__ S1,
                            const float* __restrict__ S2, const float* __restrict__ S3,
                            float* __restrict__ l1out, float* __restrict__ accs) {
    int blk = blockIdx.x;
    if (blk >= 28) {
        if (threadIdx.x < 8) accs[threadIdx.x] = 0.f;
        return;
    }
    if (blk >= 24) {
        const float* mats[4] = {S0, S1, S2, S3};
        const float* S = mats[blk - 24];
        float s = 0.f;
        for (int i = threadIdx.x; i < N_ * N_; i += 256) s += fabsf(S[i]);
        for (int off = 32; off > 0; off >>= 1) s += __shfl_down(s, off);
        __shared__ float wr[4];
        if ((threadIdx.x & 63) == 0) wr[threadIdx.x >> 6] = s;
        __syncthreads();
        if (threadIdx.x == 0) l1out[blk - 24] = wr[0] + wr[1] + wr[2] + wr[3];
        return;
    }
    int v = blk / 12, r = blk % 12;
    __shared__ float M[3][N_ * N_];
    for (int i = threadIdx.x; i < N_ * N_; i += blockDim.x) {
        float a = As_[i], f = Af_[i], t = At_[i];
        if (v) { a *= a; f *= f; t *= t; }
        M[0][i] = a; M[1][i] = f; M[2][i] = t;
    }
    __syncthreads();
    const int kind[12] = {0,0,0, 1,1,1,1,1,1, 2,2,2};
    const int ia[12]   = {0,1,2, 0,1,0,2,1,2, 0,0,2};
    const int ib[12]   = {0,1,2, 1,0,2,0,2,1, 1,2,0};
    const int ic[12]   = {0,0,0, 0,0,0,0,0,0, 2,1,1};
    const float* Ma = M[ia[r]];
    const float* Mb = M[ib[r]];
    const float* Mc = M[ic[r]];
    float* dst = (v ? A12sq : A12) + r * N_ * N_;
    for (int i = threadIdx.x; i < N_ * N_; i += blockDim.x) {
        int m = i / N_, n = i % N_;
        float acc;
        if (kind[r] == 0) {
            acc = Ma[i];
        } else if (kind[r] == 1) {
            acc = 0.f;
            for (int p = 0; p < N_; p++) acc += Ma[m*N_+p] * Mb[p*N_+n];
        } else {
            acc = 0.f;
            for (int p = 0; p < N_; p++) {
                float t = 0.f;
                for (int q = 0; q < N_; q++) t += Mb[p*N_+q] * Mc[q*N_+n];
                acc += Ma[m*N_+p] * t;
            }
        }
        dst[i] = acc;
    }
}

// ---------------- basis-composed weights, transposed to [r][o][k] bf16 ----------------
__global__ void wc_kernel(const float* __restrict__ V1, const float* __restrict__ c1,
                          const float* __restrict__ V2, const float* __restrict__ c2,
                          __bf16* __restrict__ WcT) {
    int idx = blockIdx.x * 256 + threadIdx.x;   // 12*256*128
    int k = idx & 127;
    int o = (idx >> 7) & 255;
    int r = idx >> 15;
    float acc = 0.f;
    if (k < 64) {
        for (int bb = 0; bb < 4; bb++) acc += c1[r*4+bb] * V1[((long)bb*64 + k)*256 + o];
    } else {
        int kk = k - 64;
        for (int bb = 0; bb < 4; bb++) acc += c2[r*4+bb] * V2[((long)bb*64 + kk)*256 + o];
    }
    WcT[idx] = (__bf16)acc;
}

// ---------------- GRU weight transpose: [7][512k][256n] fp32 -> [mat][g][256n][512k] bf16 ----------------
__global__ void wt_kernel(const float* __restrict__ Wr, const float* __restrict__ Wz,
                          const float* __restrict__ Wh, __bf16* __restrict__ WT) {
    int z = blockIdx.z;              // 0..20
    int mat = z / 7, g = z % 7;
    const float* srcs[3] = {Wr, Wz, Wh};
    const float* src = srcs[mat] + (long)g * 512 * 256;
    __bf16* dst = WT + ((long)mat * 7 + g) * 256 * 512;
    int n0 = blockIdx.x * 64;        // grid.x = 4
    int k0 = blockIdx.y * 64;        // grid.y = 8
    __shared__ float T[64][65];
    int c = threadIdx.x & 63, r0 = threadIdx.x >> 6;
    for (int r = r0; r < 64; r += 4)
        T[r][c] = src[(long)(k0 + r) * 256 + n0 + c];
    __syncthreads();
    for (int n = r0; n < 64; n += 4)
        dst[(long)(n0 + n) * 512 + k0 + c] = (__bf16)T[c][n];
}

// ---------------- hidden fp32 -> bf16 cast ----------------
__global__ void hcast_kernel(HPtrs hp, __bf16* __restrict__ out) {
    int g = blockIdx.y;
    long idx = ((long)blockIdx.x * 256 + threadIdx.x) * 4;   // grid.x = 2240
    float4 v = *(const float4*)(hp.p[g] + idx);
    __bf16* o = out + (long)g * ELEMS + idx;
    o[0] = (__bf16)v.x; o[1] = (__bf16)v.y; o[2] = (__bf16)v.z; o[3] = (__bf16)v.w;
}

// ---------------- xA fold: register-cached x, scalar(SGPR) A, pure v_fmac loop ----------------
// block: 4 waves = (b_local 0..1) x (v 0..1); lane = i column. grid (12, 128)
__global__ __launch_bounds__(256)
void xa_kernel(XPtrs xp, const float* __restrict__ A12, const float* __restrict__ A12sq,
               __bf16* __restrict__ xAc) {
    int r = blockIdx.x;
    int w = __builtin_amdgcn_readfirstlane(threadIdx.x >> 6);
    int v = w & 1, bl = w >> 1;
    int lane = threadIdx.x & 63;
    int b = blockIdx.y * 2 + bl;
    const float* x = xp.p[r] + (long)b * (N_ * I_);
    const float* As = (v ? A12sq : A12) + r * (N_ * N_);
    float xv[N_];
#pragma unroll
    for (int n = 0; n < N_; n++) xv[n] = x[n * I_ + lane];
    float acc[N_];
#pragma unroll
    for (int m = 0; m < N_; m++) acc[m] = 0.f;
#pragma unroll
    for (int n = 0; n < N_; n++) {
#pragma unroll
        for (int m = 0; m < N_; m++) acc[m] += As[m * N_ + n] * xv[n];
    }
    long obase = ((long)r * ROWS + (long)b * N_) * 128 + v * 64 + lane;
#pragma unroll
    for (int m = 0; m < N_; m++) xAc[obase + (long)m * 128] = (__bf16)acc[m];
}

// ---------------- bf16 MFMA GEMM, 64x64 tile, 4 waves x 32x32, batched via ptr arrays ----------
// A row-major bf16; k-split at K0 between a0[bz] (lda0) / a1[bz] (lda1).
// B is B^T row-major [N][K] bf16, n-split at N0 between B0/B1 (same ldb), z-stride bstr.
// act: 3 GRU-final (fp32 out; Zb = bf16 z at [row*512+256+col], hp = fp32 h)
//      4 split-relu sum (bf16 out)
//      5 gru-gates (bf16 out: col<256 -> sigmoid*h (rh), col>=256 -> sigmoid (z))
__global__ __launch_bounds__(256)
void gemm_bf16(GB gb, int K0, int K, int lda0, int lda1,
               const __bf16* __restrict__ B0, const __bf16* __restrict__ B1,
               int N0, int ldb, long bstr,
               void* __restrict__ Cp, int ldc, long cstr,
               int act, const __bf16* __restrict__ Zb, long zstr) {
    int bz = blockIdx.z;
    int n0 = blockIdx.x * 64;
    int m0 = blockIdx.y * 64;
    const __bf16* a0 = gb.a0[bz];
    const __bf16* a1 = gb.a1[bz];
    const __bf16* bbase = ((n0 < N0) ? B0 : B1) + bz * bstr;
    int nloc = (n0 < N0) ? n0 : (n0 - N0);
    __shared__ __bf16 As[64 * 32];
    __shared__ __bf16 Bs[64 * 32];
    int tid = threadIdx.x;
    int lane = tid & 63;
    int w = tid >> 6;
    int wm = (w & 1) * 32, wn = (w >> 1) * 32;
    int l15 = lane & 15, q = lane >> 4;
    f32x4 acc[2][2] = {};
    f32x4 accA[2][2] = {};
    int ksplit = K >> 1;

    int srow = w * 16 + (lane >> 2);
    int skoff = (lane & 3) * 8;
    __bf16* lds_a = As + w * 512;
    __bf16* lds_b = Bs + w * 512;
    const __bf16* brow = bbase + (long)(nloc + srow) * ldb + skoff;

    for (int kt = 0; kt < K; kt += 32) {
        const __bf16* aseg; int kk; int lda;
        if (kt < K0) { aseg = a0; kk = kt; lda = lda0; }
        else         { aseg = a1; kk = kt - K0; lda = lda1; }
        GLOAD_LDS16(aseg + (long)(m0 + srow) * lda + kk + skoff, lds_a);
        GLOAD_LDS16(brow + kt, lds_b);
        __syncthreads();
        bf16x8 af0 = *(const bf16x8*)(As + (wm + l15) * 32 + q * 8);
        bf16x8 af1 = *(const bf16x8*)(As + (wm + 16 + l15) * 32 + q * 8);
        bf16x8 bf0 = *(const bf16x8*)(Bs + (wn + l15) * 32 + q * 8);
        bf16x8 bf1 = *(const bf16x8*)(Bs + (wn + 16 + l15) * 32 + q * 8);
        acc[0][0] = __builtin_amdgcn_mfma_f32_16x16x32_bf16(af0, bf0, acc[0][0], 0, 0, 0);
        acc[0][1] = __builtin_amdgcn_mfma_f32_16x16x32_bf16(af0, bf1, acc[0][1], 0, 0, 0);
        acc[1][0] = __builtin_amdgcn_mfma_f32_16x16x32_bf16(af1, bf0, acc[1][0], 0, 0, 0);
        acc[1][1] = __builtin_amdgcn_mfma_f32_16x16x32_bf16(af1, bf1, acc[1][1], 0, 0, 0);
        __syncthreads();
        if (act == 4 && (kt + 32) == ksplit) {
#pragma unroll
            for (int mt = 0; mt < 2; mt++)
#pragma unroll
                for (int nt = 0; nt < 2; nt++)
#pragma unroll
                    for (int r = 0; r < 4; r++) {
                        accA[mt][nt][r] = fmaxf(acc[mt][nt][r], 0.f);
                        acc[mt][nt][r] = 0.f;
                    }
        }
    }

#pragma unroll
    for (int mt = 0; mt < 2; mt++) {
#pragma unroll
        for (int nt = 0; nt < 2; nt++) {
#pragma unroll
            for (int r = 0; r < 4; r++) {
                long row = m0 + wm + mt*16 + q*4 + r;
                int col  = n0 + wn + nt*16 + l15;
                float vv = acc[mt][nt][r];
                if (act == 3) {
                    float zz = (float)Zb[bz*zstr + row * 512 + 256 + col];
                    float hv = gb.hp[bz][row * 256 + col];
                    ((float*)Cp)[bz*cstr + row * ldc + col] = (1.f - zz) * hv + zz * tanhf(vv);
                } else if (act == 5) {
                    float s = 1.f / (1.f + expf(-vv));
                    if (col < 256) s *= gb.hp[bz][row * 256 + col];
                    ((__bf16*)Cp)[bz*cstr + row * ldc + col] = (__bf16)s;
                } else {  // act 4
                    ((__bf16*)Cp)[bz*cstr + row * ldc + col] = (__bf16)(accA[mt][nt][r] + fmaxf(vv, 0.f));
                }
            }
        }
    }
}

// ---------------- msh + sim + com, z=0..2 pairs, z=3 triple ----------------
__global__ void msh_kernel(MshA ma) {
    int z = blockIdx.z;
    bool tri = (z == 3);
    int b = blockIdx.x;
    int h0 = blockIdx.y * 64;
    __shared__ float sa[N_][64];
    __shared__ float sb[N_][64];
    __shared__ float sc[N_][64];
    __shared__ float sS[N_ * N_];
    __shared__ float wred[4];
    const __bf16* pa = ma.oa[z] + (long)b * N_ * H_;
    const __bf16* pb = ma.ob[z] + (long)b * N_ * H_;
    const __bf16* pc = ma.oc[z] + (long)b * N_ * H_;
    for (int i = threadIdx.x; i < N_ * 64; i += 256) {
        int n = i >> 6, hh = i & 63;
        sa[n][hh] = (float)pa[n*H_ + h0 + hh];
        sb[n][hh] = (float)pb[n*H_ + h0 + hh];
        if (tri) sc[n][hh] = (float)pc[n*H_ + h0 + hh];
    }
    for (int i = threadIdx.x; i < N_ * N_; i += 256) sS[i] = ma.S[z][i];
    __syncthreads();
    int hh = threadIdx.x & 63;
    int mq = threadIdx.x >> 6;
    float lsum = 0.f;
    __bf16* com = ma.com + (long)z * ELEMS;
    for (int mm = mq; mm < N_; mm += 4) {
        float a = 0.f, bb = 0.f, cc = 0.f;
        for (int n = 0; n < N_; n++) {
            float s = sS[n*N_ + mm];
            a += sa[n][hh] * s;
            bb += sb[n][hh] * s;
            if (tri) cc += sc[n][hh] * s;
        }
        long oidx = ((long)b*N_ + mm)*H_ + h0 + hh;
        if (tri) {
            com[oidx] = (__bf16)((a + bb + cc) * (1.f/3.f));
            float d1 = a-bb, d2 = a-cc, d3 = bb-cc;
            lsum += d1*d1 + d2*d2 + d3*d3;
        } else {
            com[oidx] = (__bf16)(0.5f * (a + bb));
            float d = a - bb;
            lsum += d * d;
        }
    }
    for (int off = 32; off > 0; off >>= 1) lsum += __shfl_down(lsum, off);
    if ((threadIdx.x & 63) == 0) wred[threadIdx.x >> 6] = lsum;
    __syncthreads();
    if (threadIdx.x == 0) atomicAdd(ma.accs + z, wred[0] + wred[1] + wred[2] + wred[3]);
}

// ---------------- finalize sims ----------------
__global__ void fin_kernel(const float* __restrict__ accs, float* __restrict__ outp) {
    if (threadIdx.x == 0) {
        float inv = 1.f / 2293760.f;
        outp[0] = accs[0] * inv;
        outp[1] = accs[1] * inv;
        outp[2] = accs[2] * inv;
        outp[3] = accs[3] * inv;
    }
}

extern "C" void kernel_launch(void* const* d_in, const int* in_sizes, int n_in,
                              void* d_out, int out_size, void* d_ws, size_t ws_size,
                              hipStream_t stream) {
    const float* const* in = (const float* const*)d_in;
    float* out = (float*)d_out;
    char* ws = (char*)d_ws;

    // byte-offset workspace layout (~176 MB, rhz overlays dead xAc)
    size_t off = 0;
    auto alloc = [&](size_t bytes) { size_t o = off; off += (bytes + 255) & ~(size_t)255; return o; };
    float*  A12   = (float*)(ws + alloc(12*N_*N_*4));
    float*  A12sq = (float*)(ws + alloc(12*N_*N_*4));
    __bf16* WcT   = (__bf16*)(ws + alloc((size_t)12*256*128*2));
    __bf16* WT    = (__bf16*)(ws + alloc((size_t)21*256*512*2));
    float*  accs  = (float*)(ws + alloc(256));
    __bf16* gout  = (__bf16*)(ws + alloc((size_t)12*ELEMS*2));
    __bf16* com   = (__bf16*)(ws + alloc((size_t)4*ELEMS*2));
    __bf16* hbf   = (__bf16*)(ws + alloc((size_t)7*ELEMS*2));
    size_t  tail  = alloc((size_t)7*ROWS*512*2);      // rhz region (64.2 MB)
    __bf16* rhz   = (__bf16*)(ws + tail);
    __bf16* xAc   = (__bf16*)(ws + tail);             // xAc (27.5 MB) aliases rhz; dead before gates GEMM

    XPtrs xp;
    for (int i = 0; i < 12; i++) xp.p[i] = in[i];
    HPtrs hp;
    for (int i = 0; i < 7; i++) hp.p[i] = in[15 + i];

    prep_kernel<<<29, 256, 0, stream>>>(in[12], in[13], in[14], A12, A12sq,
                                        in[27], in[26], in[28], in[29],
                                        out + 7L*ELEMS + 4, accs);
    wc_kernel<<<(12*128*256)/256, 256, 0, stream>>>(in[22], in[23], in[24], in[25], WcT);
    wt_kernel<<<dim3(4, 8, 21), 256, 0, stream>>>(in[30], in[31], in[32], WT);
    hcast_kernel<<<dim3(2240, 7), 256, 0, stream>>>(hp, hbf);
    xa_kernel<<<dim3(12, 128), 256, 0, stream>>>(xp, A12, A12sq, xAc);

    // GCN: gout[r] = relu(xA1@W1) + relu(xA2@W2)  (act=4 split-relu at K/2=64)
    {
        GB gb{};
        for (int z = 0; z < 12; z++) { gb.a0[z] = xAc + (long)z*ROWS*128; gb.a1[z] = gb.a0[z]; }
        gemm_bf16<<<dim3(4, 140, 12), 256, 0, stream>>>(
            gb, 128, 128, 128, 128,
            WcT, WcT, 256, 128, 32768L,
            gout, 256, ELEMS, 4, (const __bf16*)nullptr, 0L);
    }

    // msh + sim + com (4 batched in z)
    {
        MshA ma{};
        ma.oa[0] = gout + 3L*ELEMS; ma.ob[0] = gout + 4L*ELEMS; ma.oc[0] = ma.oa[0];
        ma.oa[1] = gout + 5L*ELEMS; ma.ob[1] = gout + 6L*ELEMS; ma.oc[1] = ma.oa[1];
        ma.oa[2] = gout + 7L*ELEMS; ma.ob[2] = gout + 8L*ELEMS; ma.oc[2] = ma.oa[2];
        ma.oa[3] = gout + 9L*ELEMS; ma.ob[3] = gout + 10L*ELEMS; ma.oc[3] = gout + 11L*ELEMS;
        ma.S[0] = in[26]; ma.S[1] = in[27]; ma.S[2] = in[28]; ma.S[3] = in[29];
        ma.com = com; ma.accs = accs;
        msh_kernel<<<dim3(256, 4, 4), 256, 0, stream>>>(ma);
    }

    fin_kernel<<<1, 64, 0, stream>>>(accs, out + 7L*ELEMS);

    // GRU gates, batched over g: rhz[g] = [sig(x1@Wr)*h | sig(x1@Wz)]  (bf16)
    {
        GB gb{};
        for (int g = 0; g < 7; g++) {
            gb.a0[g] = (g < 3) ? gout + (long)g*ELEMS : com + (long)(g - 3)*ELEMS;
            gb.a1[g] = hbf + (long)g*ELEMS;
            gb.hp[g] = in[15 + g];
        }
        gemm_bf16<<<dim3(8, 140, 7), 256, 0, stream>>>(
            gb, 256, 512, 256, 256,
            WT, WT + 7L*131072, 256, 512, 131072L,
            rhz, 512, (long)ROWS*512, 5, (const __bf16*)nullptr, 0L);
    }

    // GRU final, batched: out[g] = (1-z)*h + z*tanh([rh|o]@Wh)  (fp32 to d_out)
    {
        GB gb{};
        for (int g = 0; g < 7; g++) {
            gb.a0[g] = rhz + (long)g*ROWS*512;
            gb.a1[g] = (g < 3) ? gout + (long)g*ELEMS : com + (long)(g - 3)*ELEMS;
            gb.hp[g] = in[15 + g];
        }
        gemm_bf16<<<dim3(4, 140, 7), 256, 0, stream>>>(
            gb, 256, 512, 512, 256,
            WT + 14L*131072, WT + 14L*131072, 256, 512, 131072L,
            out, 256, ELEMS, 3, rhz, (long)ROWS*512);
    }
}

// Round 4
// 609.350 us; speedup vs baseline: 2.5196x; 1.1293x over previous
//
#include <hip/hip_runtime.h>
#include <math.h>

// Problem constants
#define B_    256
#define N_    35
#define I_    64
#define H_    256
#define ROWS  8960            // B_*N_
#define ELEMS 2293760L        // ROWS*H_

typedef __bf16 bf16x8 __attribute__((ext_vector_type(8)));
typedef float f32x4 __attribute__((ext_vector_type(4)));

struct XPtrs { const float* p[12]; };
struct HPtrs { const float* p[7]; };
struct GB    { const __bf16* a0[12]; const __bf16* a1[12]; const float* hp[12]; };
struct MshA  { const __bf16* oa[4]; const __bf16* ob[4]; const __bf16* oc[4];
               const float* S[4]; __bf16* com; float* accs; };

#define GLOAD_LDS16(g, l) __builtin_amdgcn_global_load_lds( \
    (const __attribute__((address_space(1))) unsigned int*)(g), \
    (__attribute__((address_space(3))) unsigned int*)(l), 16, 0, 0)

// ---------------- prep: zero accs (blk 28) + compose adjacencies (blk 0..23) + L1 (blk 24..27) ----
__global__ void prep_kernel(const float* __restrict__ As_, const float* __restrict__ Af_,
                            const float* __restrict__ At_, float* __restrict__ A12,
                            float* __restrict__ A12sq,
                            const float* __restrict__ S0, const float* __restrict__ S1,
                            const float* __restrict__ S2, const float* __restrict__ S3,
                            float* __restrict__ l1out, float* __restrict__ accs) {
    int blk = blockIdx.x;
    if (blk >= 28) {
        if (threadIdx.x < 8) accs[threadIdx.x] = 0.f;
        return;
    }
    if (blk >= 24) {
        const float* mats[4] = {S0, S1, S2, S3};
        const float* S = mats[blk - 24];
        float s = 0.f;
        for (int i = threadIdx.x; i < N_ * N_; i += 256) s += fabsf(S[i]);
        for (int off = 32; off > 0; off >>= 1) s += __shfl_down(s, off);
        __shared__ float wr[4];
        if ((threadIdx.x & 63) == 0) wr[threadIdx.x >> 6] = s;
        __syncthreads();
        if (threadIdx.x == 0) l1out[blk - 24] = wr[0] + wr[1] + wr[2] + wr[3];
        return;
    }
    int v = blk / 12, r = blk % 12;
    __shared__ float M[3][N_ * N_];
    for (int i = threadIdx.x; i < N_ * N_; i += blockDim.x) {
        float a = As_[i], f = Af_[i], t = At_[i];
        if (v) { a *= a; f *= f; t *= t; }
        M[0][i] = a; M[1][i] = f; M[2][i] = t;
    }
    __syncthreads();
    const int kind[12] = {0,0,0, 1,1,1,1,1,1, 2,2,2};
    const int ia[12]   = {0,1,2, 0,1,0,2,1,2, 0,0,2};
    const int ib[12]   = {0,1,2, 1,0,2,0,2,1, 1,2,0};
    const int ic[12]   = {0,0,0, 0,0,0,0,0,0, 2,1,1};
    const float* Ma = M[ia[r]];
    const float* Mb = M[ib[r]];
    const float* Mc = M[ic[r]];
    float* dst = (v ? A12sq : A12) + r * N_ * N_;
    for (int i = threadIdx.x; i < N_ * N_; i += blockDim.x) {
        int m = i / N_, n = i % N_;
        float acc;
        if (kind[r] == 0) {
            acc = Ma[i];
        } else if (kind[r] == 1) {
            acc = 0.f;
            for (int p = 0; p < N_; p++) acc += Ma[m*N_+p] * Mb[p*N_+n];
        } else {
            acc = 0.f;
            for (int p = 0; p < N_; p++) {
                float t = 0.f;
                for (int q = 0; q < N_; q++) t += Mb[p*N_+q] * Mc[q*N_+n];
                acc += Ma[m*N_+p] * t;
            }
        }
        dst[i] = acc;
    }
}

// ---------------- basis-composed weights, transposed to [r][o][k] bf16 ----------------
__global__ void wc_kernel(const float* __restrict__ V1, const float* __restrict__ c1,
                          const float* __restrict__ V2, const float* __restrict__ c2,
                          __bf16* __restrict__ WcT) {
    int idx = blockIdx.x * 256 + threadIdx.x;   // 12*256*128
    int k = idx & 127;
    int o = (idx >> 7) & 255;
    int r = idx >> 15;
    float acc = 0.f;
    if (k < 64) {
        for (int bb = 0; bb < 4; bb++) acc += c1[r*4+bb] * V1[((long)bb*64 + k)*256 + o];
    } else {
        int kk = k - 64;
        for (int bb = 0; bb < 4; bb++) acc += c2[r*4+bb] * V2[((long)bb*64 + kk)*256 + o];
    }
    WcT[idx] = (__bf16)acc;
}

// ---------------- GRU weight transpose: [7][512k][256n] fp32 -> [mat][g][256n][512k] bf16 ----------------
__global__ void wt_kernel(const float* __restrict__ Wr, const float* __restrict__ Wz,
                          const float* __restrict__ Wh, __bf16* __restrict__ WT) {
    int z = blockIdx.z;              // 0..20
    int mat = z / 7, g = z % 7;
    const float* srcs[3] = {Wr, Wz, Wh};
    const float* src = srcs[mat] + (long)g * 512 * 256;
    __bf16* dst = WT + ((long)mat * 7 + g) * 256 * 512;
    int n0 = blockIdx.x * 64;        // grid.x = 4
    int k0 = blockIdx.y * 64;        // grid.y = 8
    __shared__ float T[64][65];
    int c = threadIdx.x & 63, r0 = threadIdx.x >> 6;
    for (int r = r0; r < 64; r += 4)
        T[r][c] = src[(long)(k0 + r) * 256 + n0 + c];
    __syncthreads();
    for (int n = r0; n < 64; n += 4)
        dst[(long)(n0 + n) * 512 + k0 + c] = (__bf16)T[c][n];
}

// ---------------- hidden fp32 -> bf16 cast ----------------
__global__ void hcast_kernel(HPtrs hp, __bf16* __restrict__ out) {
    int g = blockIdx.y;
    long idx = ((long)blockIdx.x * 256 + threadIdx.x) * 4;   // grid.x = 2240
    float4 v = *(const float4*)(hp.p[g] + idx);
    __bf16* o = out + (long)g * ELEMS + idx;
    o[0] = (__bf16)v.x; o[1] = (__bf16)v.y; o[2] = (__bf16)v.z; o[3] = (__bf16)v.w;
}

// ---------------- xA fold: register-cached x, scalar(SGPR) A, pure v_fmac loop ----------------
__global__ __launch_bounds__(256)
void xa_kernel(XPtrs xp, const float* __restrict__ A12, const float* __restrict__ A12sq,
               __bf16* __restrict__ xAc) {
    int r = blockIdx.x;
    int w = __builtin_amdgcn_readfirstlane(threadIdx.x >> 6);
    int v = w & 1, bl = w >> 1;
    int lane = threadIdx.x & 63;
    int b = blockIdx.y * 2 + bl;
    const float* x = xp.p[r] + (long)b * (N_ * I_);
    const float* As = (v ? A12sq : A12) + r * (N_ * N_);
    float xv[N_];
#pragma unroll
    for (int n = 0; n < N_; n++) xv[n] = x[n * I_ + lane];
    float acc[N_];
#pragma unroll
    for (int m = 0; m < N_; m++) acc[m] = 0.f;
#pragma unroll
    for (int n = 0; n < N_; n++) {
#pragma unroll
        for (int m = 0; m < N_; m++) acc[m] += As[m * N_ + n] * xv[n];
    }
    long obase = ((long)r * ROWS + (long)b * N_) * 128 + v * 64 + lane;
#pragma unroll
    for (int m = 0; m < N_; m++) xAc[obase + (long)m * 128] = (__bf16)acc[m];
}

// ---------------- bf16 MFMA GEMM, 128x128 tile (m97 structure), 4 waves x 64x64 ----------
// A row-major bf16; k-split at K0 between a0[bz] (lda0) / a1[bz] (lda1).
// B is B^T row-major [N][K] bf16, n-split at N0 between B0/B1 (same ldb), z-stride bstr.
// ACT: 3 GRU-final (fp32 out; Zb bf16 z at [row*512+256+col], hp fp32 h)
//      4 split-relu sum (bf16 out)
//      5 gru-gates (bf16 out: col<256 -> sigmoid*h, col>=256 -> sigmoid)
template<int ACT>
__global__ __launch_bounds__(256)
void gemm_bf16(GB gb, int K0, int K, int lda0, int lda1,
               const __bf16* __restrict__ B0, const __bf16* __restrict__ B1,
               int N0, int ldb, long bstr,
               void* __restrict__ Cp, int ldc, long cstr,
               const __bf16* __restrict__ Zb, long zstr) {
    int bz = blockIdx.z;
    int n0 = blockIdx.x * 128;
    int m0 = blockIdx.y * 128;
    const __bf16* a0 = gb.a0[bz];
    const __bf16* a1 = gb.a1[bz];
    const __bf16* bbase = ((n0 < N0) ? B0 : B1) + bz * bstr;
    int nloc = (n0 < N0) ? n0 : (n0 - N0);
    __shared__ __bf16 As[128 * 32];
    __shared__ __bf16 Bs[128 * 32];
    int tid = threadIdx.x;
    int lane = tid & 63;
    int w = tid >> 6;
    int wm = (w & 1) * 64, wn = (w >> 1) * 64;
    int l15 = lane & 15, q = lane >> 4;
    f32x4 acc[4][4] = {};
    f32x4 accA[4][4];   // only live for ACT==4
    int ksplit = K >> 1;

    int srow = w * 16 + (lane >> 2);     // row within 64-row pass
    int skoff = (lane & 3) * 8;          // k-offset (elements)
    __bf16* lda_lds0 = As + w * 512;
    __bf16* lda_lds1 = As + 2048 + w * 512;
    __bf16* ldb_lds0 = Bs + w * 512;
    __bf16* ldb_lds1 = Bs + 2048 + w * 512;
    const __bf16* brow0 = bbase + (long)(nloc + srow) * ldb + skoff;
    const __bf16* brow1 = bbase + (long)(nloc + srow + 64) * ldb + skoff;

    for (int kt = 0; kt < K; kt += 32) {
        const __bf16* aseg; int kk; int lda;
        if (kt < K0) { aseg = a0; kk = kt; lda = lda0; }
        else         { aseg = a1; kk = kt - K0; lda = lda1; }
        GLOAD_LDS16(aseg + (long)(m0 + srow) * lda + kk + skoff, lda_lds0);
        GLOAD_LDS16(aseg + (long)(m0 + srow + 64) * lda + kk + skoff, lda_lds1);
        GLOAD_LDS16(brow0 + kt, ldb_lds0);
        GLOAD_LDS16(brow1 + kt, ldb_lds1);
        __syncthreads();
        bf16x8 af[4], bfr[4];
#pragma unroll
        for (int mt = 0; mt < 4; mt++) af[mt] = *(const bf16x8*)(As + (wm + mt*16 + l15) * 32 + q * 8);
#pragma unroll
        for (int nt = 0; nt < 4; nt++) bfr[nt] = *(const bf16x8*)(Bs + (wn + nt*16 + l15) * 32 + q * 8);
#pragma unroll
        for (int mt = 0; mt < 4; mt++)
#pragma unroll
            for (int nt = 0; nt < 4; nt++)
                acc[mt][nt] = __builtin_amdgcn_mfma_f32_16x16x32_bf16(af[mt], bfr[nt], acc[mt][nt], 0, 0, 0);
        __syncthreads();
        if (ACT == 4 && (kt + 32) == ksplit) {
#pragma unroll
            for (int mt = 0; mt < 4; mt++)
#pragma unroll
                for (int nt = 0; nt < 4; nt++)
#pragma unroll
                    for (int r = 0; r < 4; r++) {
                        accA[mt][nt][r] = fmaxf(acc[mt][nt][r], 0.f);
                        acc[mt][nt][r] = 0.f;
                    }
        }
    }

#pragma unroll
    for (int mt = 0; mt < 4; mt++) {
#pragma unroll
        for (int nt = 0; nt < 4; nt++) {
#pragma unroll
            for (int r = 0; r < 4; r++) {
                long row = m0 + wm + mt*16 + q*4 + r;
                int col  = n0 + wn + nt*16 + l15;
                float vv = acc[mt][nt][r];
                if (ACT == 3) {
                    float zz = (float)Zb[bz*zstr + row * 512 + 256 + col];
                    float hv = gb.hp[bz][row * 256 + col];
                    ((float*)Cp)[bz*cstr + row * ldc + col] = (1.f - zz) * hv + zz * tanhf(vv);
                } else if (ACT == 5) {
                    float s = 1.f / (1.f + expf(-vv));
                    if (col < 256) s *= gb.hp[bz][row * 256 + col];
                    ((__bf16*)Cp)[bz*cstr + row * ldc + col] = (__bf16)s;
                } else {  // ACT 4
                    ((__bf16*)Cp)[bz*cstr + row * ldc + col] = (__bf16)(accA[mt][nt][r] + fmaxf(vv, 0.f));
                }
            }
        }
    }
}

// ---------------- msh + sim + com: register-cached o, scalar S, pure v_fmac ----------------
// grid (256 b, 4 h-tile, 4 z); wave w handles nodes mm = w, w+4, ...
__global__ __launch_bounds__(256, 1)
void msh_kernel(MshA ma) {
    int z = blockIdx.z;
    bool tri = (z == 3);
    int b = blockIdx.x;
    int h0 = blockIdx.y * 64;
    int lane = threadIdx.x & 63;
    int w = __builtin_amdgcn_readfirstlane(threadIdx.x >> 6);
    long base = (long)b * N_ * H_ + h0 + lane;
    const __bf16* pa = ma.oa[z] + base;
    const __bf16* pb = ma.ob[z] + base;
    const __bf16* pc = ma.oc[z] + base;
    float av[N_], bv[N_], cv[N_];
#pragma unroll
    for (int n = 0; n < N_; n++) {
        av[n] = (float)pa[n * H_];
        bv[n] = (float)pb[n * H_];
    }
    if (tri) {
#pragma unroll
        for (int n = 0; n < N_; n++) cv[n] = (float)pc[n * H_];
    }
    const float* S = ma.S[z];
    __bf16* com = ma.com + (long)z * ELEMS + base;
    float lsum = 0.f;
    for (int mm = w; mm < N_; mm += 4) {        // mm wave-uniform
        float a = 0.f, bb = 0.f, cc = 0.f;
#pragma unroll
        for (int n = 0; n < N_; n++) {
            float s = S[n * N_ + mm];           // uniform -> s_load
            a += av[n] * s;
            bb += bv[n] * s;
            if (tri) cc += cv[n] * s;
        }
        if (tri) {
            com[(long)mm * H_] = (__bf16)((a + bb + cc) * (1.f/3.f));
            float d1 = a - bb, d2 = a - cc, d3 = bb - cc;
            lsum += d1*d1 + d2*d2 + d3*d3;
        } else {
            com[(long)mm * H_] = (__bf16)(0.5f * (a + bb));
            float d = a - bb;
            lsum += d * d;
        }
    }
    for (int off = 32; off > 0; off >>= 1) lsum += __shfl_down(lsum, off);
    __shared__ float wred[4];
    if (lane == 0) wred[w] = lsum;
    __syncthreads();
    if (threadIdx.x == 0) atomicAdd(ma.accs + z, wred[0] + wred[1] + wred[2] + wred[3]);
}

// ---------------- finalize sims ----------------
__global__ void fin_kernel(const float* __restrict__ accs, float* __restrict__ outp) {
    if (threadIdx.x == 0) {
        float inv = 1.f / 2293760.f;
        outp[0] = accs[0] * inv;
        outp[1] = accs[1] * inv;
        outp[2] = accs[2] * inv;
        outp[3] = accs[3] * inv;
    }
}

extern "C" void kernel_launch(void* const* d_in, const int* in_sizes, int n_in,
                              void* d_out, int out_size, void* d_ws, size_t ws_size,
                              hipStream_t stream) {
    const float* const* in = (const float* const*)d_in;
    float* out = (float*)d_out;
    char* ws = (char*)d_ws;

    size_t off = 0;
    auto alloc = [&](size_t bytes) { size_t o = off; off += (bytes + 255) & ~(size_t)255; return o; };
    float*  A12   = (float*)(ws + alloc(12*N_*N_*4));
    float*  A12sq = (float*)(ws + alloc(12*N_*N_*4));
    __bf16* WcT   = (__bf16*)(ws + alloc((size_t)12*256*128*2));
    __bf16* WT    = (__bf16*)(ws + alloc((size_t)21*256*512*2));
    float*  accs  = (float*)(ws + alloc(256));
    __bf16* gout  = (__bf16*)(ws + alloc((size_t)12*ELEMS*2));
    __bf16* com   = (__bf16*)(ws + alloc((size_t)4*ELEMS*2));
    __bf16* hbf   = (__bf16*)(ws + alloc((size_t)7*ELEMS*2));
    size_t  tail  = alloc((size_t)7*ROWS*512*2);      // rhz region (64.2 MB)
    __bf16* rhz   = (__bf16*)(ws + tail);
    __bf16* xAc   = (__bf16*)(ws + tail);             // aliases rhz; dead before gates GEMM

    XPtrs xp;
    for (int i = 0; i < 12; i++) xp.p[i] = in[i];
    HPtrs hp;
    for (int i = 0; i < 7; i++) hp.p[i] = in[15 + i];

    prep_kernel<<<29, 256, 0, stream>>>(in[12], in[13], in[14], A12, A12sq,
                                        in[27], in[26], in[28], in[29],
                                        out + 7L*ELEMS + 4, accs);
    wc_kernel<<<(12*128*256)/256, 256, 0, stream>>>(in[22], in[23], in[24], in[25], WcT);
    wt_kernel<<<dim3(4, 8, 21), 256, 0, stream>>>(in[30], in[31], in[32], WT);
    hcast_kernel<<<dim3(2240, 7), 256, 0, stream>>>(hp, hbf);
    xa_kernel<<<dim3(12, 128), 256, 0, stream>>>(xp, A12, A12sq, xAc);

    // GCN: gout[r] = relu(xA1@W1) + relu(xA2@W2)  (ACT=4 split-relu at K/2=64)
    {
        GB gb{};
        for (int z = 0; z < 12; z++) { gb.a0[z] = xAc + (long)z*ROWS*128; gb.a1[z] = gb.a0[z]; }
        gemm_bf16<4><<<dim3(2, 70, 12), 256, 0, stream>>>(
            gb, 128, 128, 128, 128,
            WcT, WcT, 256, 128, 32768L,
            gout, 256, ELEMS, (const __bf16*)nullptr, 0L);
    }

    // msh + sim + com (4 batched in z)
    {
        MshA ma{};
        ma.oa[0] = gout + 3L*ELEMS; ma.ob[0] = gout + 4L*ELEMS; ma.oc[0] = ma.oa[0];
        ma.oa[1] = gout + 5L*ELEMS; ma.ob[1] = gout + 6L*ELEMS; ma.oc[1] = ma.oa[1];
        ma.oa[2] = gout + 7L*ELEMS; ma.ob[2] = gout + 8L*ELEMS; ma.oc[2] = ma.oa[2];
        ma.oa[3] = gout + 9L*ELEMS; ma.ob[3] = gout + 10L*ELEMS; ma.oc[3] = gout + 11L*ELEMS;
        ma.S[0] = in[26]; ma.S[1] = in[27]; ma.S[2] = in[28]; ma.S[3] = in[29];
        ma.com = com; ma.accs = accs;
        msh_kernel<<<dim3(256, 4, 4), 256, 0, stream>>>(ma);
    }

    fin_kernel<<<1, 64, 0, stream>>>(accs, out + 7L*ELEMS);

    // GRU gates, batched over g: rhz[g] = [sig(x1@Wr)*h | sig(x1@Wz)]  (bf16)
    {
        GB gb{};
        for (int g = 0; g < 7; g++) {
            gb.a0[g] = (g < 3) ? gout + (long)g*ELEMS : com + (long)(g - 3)*ELEMS;
            gb.a1[g] = hbf + (long)g*ELEMS;
            gb.hp[g] = in[15 + g];
        }
        gemm_bf16<5><<<dim3(4, 70, 7), 256, 0, stream>>>(
            gb, 256, 512, 256, 256,
            WT, WT + 7L*131072, 256, 512, 131072L,
            rhz, 512, (long)ROWS*512, (const __bf16*)nullptr, 0L);
    }

    // GRU final, batched: out[g] = (1-z)*h + z*tanh([rh|o]@Wh)  (fp32 to d_out)
    {
        GB gb{};
        for (int g = 0; g < 7; g++) {
            gb.a0[g] = rhz + (long)g*ROWS*512;
            gb.a1[g] = (g < 3) ? gout + (long)g*ELEMS : com + (long)(g - 3)*ELEMS;
            gb.hp[g] = in[15 + g];
        }
        gemm_bf16<3><<<dim3(2, 70, 7), 256, 0, stream>>>(
            gb, 256, 512, 512, 256,
            WT + 14L*131072, WT + 14L*131072, 256, 512, 131072L,
            out, 256, ELEMS, rhz, (long)ROWS*512);
    }
}